// Round 1
// baseline (434.191 us; speedup 1.0000x reference)
//
#include <hip/hip_runtime.h>

#define S_  512
#define B_  256
#define NIN 180
#define NH  8
#define NG  32   // 4*NH

__device__ __forceinline__ float fsig(float x) {
    // 1/(1+e^-x) via hardware exp2/rcp
    return __builtin_amdgcn_rcpf(1.0f + __builtin_amdgcn_exp2f(-1.4426950408889634f * x));
}
__device__ __forceinline__ float ftanh(float x) {
    // tanh(x) = 1 - 2/(1+e^{2x})
    return 1.0f - 2.0f * __builtin_amdgcn_rcpf(1.0f + __builtin_amdgcn_exp2f(2.8853900817779268f * x));
}

// Kernel A: xg[s,b,g] = sum_i x[s,b,i]*w_ih0[g,i] + b_ih0[g] + b_hh0[g]
// One block = 64 rows of x (rows are (s,b) pairs). Thread = (row-pair, gate-quad).
__global__ __launch_bounds__(256) void xg_gemm(
    const float* __restrict__ x, const float* __restrict__ w,
    const float* __restrict__ bi, const float* __restrict__ bh,
    float* __restrict__ xg)
{
    __shared__ float wt[NIN][NG];   // transposed: wt[i][g] -> conflict-free b128 reads
    __shared__ float bias[NG];
    const int tid = threadIdx.x;
    for (int idx = tid; idx < NIN * NG; idx += 256) {
        int g = idx / NIN, i = idx - g * NIN;
        wt[i][g] = w[idx];
    }
    if (tid < NG) bias[tid] = bi[tid] + bh[tid];
    __syncthreads();

    const int rp = tid >> 3;        // 0..31 row-pair within block
    const int gq = tid & 7;         // gate quad: gates 4*gq..4*gq+3
    const long long row0 = (long long)blockIdx.x * 64 + rp * 2;
    const float4* xr0 = (const float4*)(x + row0 * NIN);
    const float4* xr1 = (const float4*)(x + (row0 + 1) * NIN);

    float a00 = 0.f, a01 = 0.f, a02 = 0.f, a03 = 0.f;
    float a10 = 0.f, a11 = 0.f, a12 = 0.f, a13 = 0.f;
    #pragma unroll 5
    for (int ii = 0; ii < 45; ++ii) {
        float4 xa = xr0[ii];
        float4 xb = xr1[ii];
        #pragma unroll
        for (int e = 0; e < 4; ++e) {
            float4 wv = *(const float4*)&wt[4 * ii + e][gq * 4];
            float xae = (e == 0) ? xa.x : (e == 1) ? xa.y : (e == 2) ? xa.z : xa.w;
            float xbe = (e == 0) ? xb.x : (e == 1) ? xb.y : (e == 2) ? xb.z : xb.w;
            a00 += xae * wv.x; a01 += xae * wv.y; a02 += xae * wv.z; a03 += xae * wv.w;
            a10 += xbe * wv.x; a11 += xbe * wv.y; a12 += xbe * wv.z; a13 += xbe * wv.w;
        }
    }
    float4 b4 = *(const float4*)&bias[gq * 4];
    float4 o0 = {a00 + b4.x, a01 + b4.y, a02 + b4.z, a03 + b4.w};
    float4 o1 = {a10 + b4.x, a11 + b4.y, a12 + b4.z, a13 + b4.w};
    *(float4*)&xg[row0 * NG + gq * 4] = o0;
    *(float4*)&xg[(row0 + 1) * NG + gq * 4] = o1;
}

// Kernel B: fused 2-layer LSTM scan + output projection.
// 8 lanes per batch chain; lane j owns hidden unit j (computes its 4 gates).
__global__ __launch_bounds__(64) void lstm_scan(
    const float* __restrict__ xg,
    const float* __restrict__ w_hh0,
    const float* __restrict__ w_ih1, const float* __restrict__ w_hh1,
    const float* __restrict__ b_ih1, const float* __restrict__ b_hh1,
    const float* __restrict__ w_reg, const float* __restrict__ b_reg,
    float* __restrict__ out)
{
    const int tid = blockIdx.x * 64 + threadIdx.x;
    const int b = tid >> 3;         // batch 0..255
    const int j = tid & 7;          // hidden unit

    // per-lane weights (all unrolled -> registers)
    float w0[4][8], wi1[4][8], wh1[4][8], bs1[4];
    #pragma unroll
    for (int q = 0; q < 4; ++q) {
        const int g = q * NH + j;
        #pragma unroll
        for (int k = 0; k < 8; ++k) {
            w0[q][k]  = w_hh0[g * NH + k];
            wi1[q][k] = w_ih1[g * NH + k];
            wh1[q][k] = w_hh1[g * NH + k];
        }
        bs1[q] = b_ih1[g] + b_hh1[g];
    }
    const float wr0 = w_reg[j], wr1 = w_reg[NH + j];
    const float br0 = b_reg[0], br1 = b_reg[1];

    float h0 = 0.f, c0 = 0.f, h1 = 0.f, c1 = 0.f;
    const float* xgp = xg + (size_t)b * NG;
    float* outp = out + (size_t)b * 2;

    for (int t = 0; t < S_; ++t) {
        // ---- layer 0 ----
        float ai = xgp[j], af = xgp[NH + j], ag = xgp[2 * NH + j], ao = xgp[3 * NH + j];
        #pragma unroll
        for (int k = 0; k < 8; ++k) {
            float hk = __shfl(h0, k, 8);
            ai += w0[0][k] * hk; af += w0[1][k] * hk;
            ag += w0[2][k] * hk; ao += w0[3][k] * hk;
        }
        float i0 = fsig(ai), f0 = fsig(af), g0 = ftanh(ag), o0 = fsig(ao);
        c0 = f0 * c0 + i0 * g0;
        h0 = o0 * ftanh(c0);

        // ---- layer 1 ----
        ai = bs1[0]; af = bs1[1]; ag = bs1[2]; ao = bs1[3];
        #pragma unroll
        for (int k = 0; k < 8; ++k) {
            float hk0 = __shfl(h0, k, 8);
            float hk1 = __shfl(h1, k, 8);
            ai += wi1[0][k] * hk0 + wh1[0][k] * hk1;
            af += wi1[1][k] * hk0 + wh1[1][k] * hk1;
            ag += wi1[2][k] * hk0 + wh1[2][k] * hk1;
            ao += wi1[3][k] * hk0 + wh1[3][k] * hk1;
        }
        float i1 = fsig(ai), f1 = fsig(af), g1 = ftanh(ag), o1 = fsig(ao);
        c1 = f1 * c1 + i1 * g1;
        h1 = o1 * ftanh(c1);

        // ---- projection: y = h1 @ w_reg^T + b_reg ----
        float p0 = h1 * wr0, p1 = h1 * wr1;
        #pragma unroll
        for (int m = 4; m >= 1; m >>= 1) {
            p0 += __shfl_xor(p0, m, 8);
            p1 += __shfl_xor(p1, m, 8);
        }
        if (j == 0) {
            float2 o = {p0 + br0, p1 + br1};
            *(float2*)outp = o;
        }
        xgp  += B_ * NG;
        outp += B_ * 2;
    }
}

extern "C" void kernel_launch(void* const* d_in, const int* in_sizes, int n_in,
                              void* d_out, int out_size, void* d_ws, size_t ws_size,
                              hipStream_t stream) {
    (void)in_sizes; (void)n_in; (void)out_size; (void)ws_size;
    const float* x     = (const float*)d_in[0];
    const float* w_ih0 = (const float*)d_in[1];
    const float* w_hh0 = (const float*)d_in[2];
    const float* b_ih0 = (const float*)d_in[3];
    const float* b_hh0 = (const float*)d_in[4];
    const float* w_ih1 = (const float*)d_in[5];
    const float* w_hh1 = (const float*)d_in[6];
    const float* b_ih1 = (const float*)d_in[7];
    const float* b_hh1 = (const float*)d_in[8];
    const float* w_reg = (const float*)d_in[9];
    const float* b_reg = (const float*)d_in[10];
    float* out = (float*)d_out;
    float* xg  = (float*)d_ws;   // 512*256*32*4 = 16 MB scratch

    xg_gemm<<<2048, 256, 0, stream>>>(x, w_ih0, b_ih0, b_hh0, xg);
    lstm_scan<<<32, 64, 0, stream>>>(xg, w_hh0, w_ih1, w_hh1, b_ih1, b_hh1,
                                     w_reg, b_reg, out);
}

// Round 2
// 184.095 us; speedup vs baseline: 2.3585x; 2.3585x over previous
//
#include <hip/hip_runtime.h>

#define S_  512
#define B_  256
#define NIN 180
#define NH  8
#define NG  32   // 4*NH

// ---- ds_swizzle helpers (BitMode: offset = xor<<10 | or<<5 | and) ----
template<int PAT>
__device__ __forceinline__ float swz(float v) {
    return __uint_as_float((unsigned)__builtin_amdgcn_ds_swizzle((int)__float_as_uint(v), PAT));
}
// broadcast lane ((lane&0x18)|k) within each 8-group of a 32-lane half
#define BCAST8(v, o) do { \
    o[0]=swz<0x0018>(v); o[1]=swz<0x0038>(v); o[2]=swz<0x0058>(v); o[3]=swz<0x0078>(v); \
    o[4]=swz<0x0098>(v); o[5]=swz<0x00B8>(v); o[6]=swz<0x00D8>(v); o[7]=swz<0x00F8>(v); \
} while (0)

// Kernel A: xg[s,b,g] = sum_i x[s,b,i]*w_ih0[g,i] + b_ih0[g] + b_hh0[g]
__global__ __launch_bounds__(256) void xg_gemm(
    const float* __restrict__ x, const float* __restrict__ w,
    const float* __restrict__ bi, const float* __restrict__ bh,
    float* __restrict__ xg)
{
    __shared__ float wt[NIN][NG];   // transposed: wt[i][g]
    __shared__ float bias[NG];
    const int tid = threadIdx.x;
    for (int idx = tid; idx < NIN * NG; idx += 256) {
        int g = idx / NIN, i = idx - g * NIN;
        wt[i][g] = w[idx];
    }
    if (tid < NG) bias[tid] = bi[tid] + bh[tid];
    __syncthreads();

    const int rp = tid >> 3;
    const int gq = tid & 7;
    const long long row0 = (long long)blockIdx.x * 64 + rp * 2;
    const float4* xr0 = (const float4*)(x + row0 * NIN);
    const float4* xr1 = (const float4*)(x + (row0 + 1) * NIN);

    float a00 = 0.f, a01 = 0.f, a02 = 0.f, a03 = 0.f;
    float a10 = 0.f, a11 = 0.f, a12 = 0.f, a13 = 0.f;
    #pragma unroll 5
    for (int ii = 0; ii < 45; ++ii) {
        float4 xa = xr0[ii];
        float4 xb = xr1[ii];
        #pragma unroll
        for (int e = 0; e < 4; ++e) {
            float4 wv = *(const float4*)&wt[4 * ii + e][gq * 4];
            float xae = (e == 0) ? xa.x : (e == 1) ? xa.y : (e == 2) ? xa.z : xa.w;
            float xbe = (e == 0) ? xb.x : (e == 1) ? xb.y : (e == 2) ? xb.z : xb.w;
            a00 += xae * wv.x; a01 += xae * wv.y; a02 += xae * wv.z; a03 += xae * wv.w;
            a10 += xbe * wv.x; a11 += xbe * wv.y; a12 += xbe * wv.z; a13 += xbe * wv.w;
        }
    }
    float4 b4 = *(const float4*)&bias[gq * 4];
    float4 o0 = {a00 + b4.x, a01 + b4.y, a02 + b4.z, a03 + b4.w};
    float4 o1 = {a10 + b4.x, a11 + b4.y, a12 + b4.z, a13 + b4.w};
    *(float4*)&xg[row0 * NG + gq * 4] = o0;
    *(float4*)&xg[(row0 + 1) * NG + gq * 4] = o1;
}

// Kernel B: fused 2-layer LSTM + projection, 32 lanes/chain (lane = gate),
// layer-overlapped software pipeline + 8-deep xg prefetch.
__global__ __launch_bounds__(64) void lstm_scan(
    const float* __restrict__ xg,
    const float* __restrict__ w_hh0,
    const float* __restrict__ w_ih1, const float* __restrict__ w_hh1,
    const float* __restrict__ b_ih1, const float* __restrict__ b_hh1,
    const float* __restrict__ w_reg, const float* __restrict__ b_reg,
    float* __restrict__ out)
{
    const int lt   = threadIdx.x;
    const int lane = lt & 31;          // gate index g = q*8+j
    const int q    = lane >> 3;        // gate class: 0=i 1=f 2=g 3=o
    const int b    = (blockIdx.x * 64 + lt) >> 5;
    const int col  = lane >> 3;        // 0 or 1 for store lanes
    const bool isl = (lane == 0) || (lane == 8);
    const bool q0b = (q & 1) != 0;
    const bool q1b = (q & 2) != 0;

    // per-lane weights (gate row g = lane)
    float w0[8], wi1[8], wh1[8], wrq[8];
    *(float4*)(w0)     = *(const float4*)(w_hh0 + lane * 8);
    *(float4*)(w0 + 4) = *(const float4*)(w_hh0 + lane * 8 + 4);
    *(float4*)(wi1)     = *(const float4*)(w_ih1 + lane * 8);
    *(float4*)(wi1 + 4) = *(const float4*)(w_ih1 + lane * 8 + 4);
    *(float4*)(wh1)     = *(const float4*)(w_hh1 + lane * 8);
    *(float4*)(wh1 + 4) = *(const float4*)(w_hh1 + lane * 8 + 4);
    const int cc = q & 1;
    *(float4*)(wrq)     = *(const float4*)(w_reg + cc * 8);
    *(float4*)(wrq + 4) = *(const float4*)(w_reg + cc * 8 + 4);
    const float br  = b_reg[cc];
    const float b1s = b_ih1[lane] + b_hh1[lane];

    // branch-free activation constants: sigmoid for q!=2, tanh for q==2
    const float sA = (q == 2) ? -2.8853900817779268f : -1.4426950408889634f;
    const float aA = (q == 2) ? 2.0f : 1.0f;
    const float bA = (q == 2) ? -1.0f : 0.0f;

    auto actv = [&](float x) {
        return __builtin_fmaf(aA, __builtin_amdgcn_rcpf(1.0f + __builtin_amdgcn_exp2f(sA * x)), bA);
    };
    auto tanhc = [](float x) {
        return __builtin_fmaf(2.0f, __builtin_amdgcn_rcpf(1.0f + __builtin_amdgcn_exp2f(-2.8853900817779268f * x)), -1.0f);
    };

    float h0p = 0.f, h1p = 0.f, c0 = 0.f, c1 = 0.f;

    // 8-deep prefetch of xg: one coalesced scalar per lane per step
    float xq[8];
    {
        const float* x0 = xg + (size_t)b * NG + lane;
        #pragma unroll
        for (int k = 0; k < 8; ++k) xq[k] = x0[(size_t)k * (B_ * NG)];
    }
    const float* xp = xg + ((size_t)8 * B_ + b) * NG + lane;  // next prefetch: step 8
    float* op = out + (size_t)b * 2 + col;                    // row (u-2)=0

    // instance u: layer0(u) || layer1(u-1) || proj(u-2)
    auto STEP = [&](float& xr, bool l1on, bool doproj, bool pref) {
        float hk[8], hj[8];
        BCAST8(h0p, hk);   // h0(u-1) -> all lanes
        BCAST8(h1p, hj);   // h1(u-2) -> all lanes
        float a0 = xr;
        if (pref) { xr = *xp; xp += B_ * NG; }
        #pragma unroll
        for (int k = 0; k < 8; ++k) a0 = __builtin_fmaf(w0[k], hk[k], a0);
        float t0 = actv(a0);
        float v8  = swz<0x201F>(t0);   // class q^1
        float v16 = swz<0x401F>(t0);   // class q^2
        float v24 = swz<0x601F>(t0);   // class q^3
        float gi = q1b ? (q0b ? v24 : v16) : (q0b ? v8  : t0 );
        float gf = q1b ? (q0b ? v16 : v24) : (q0b ? t0  : v8 );
        float gg = q1b ? (q0b ? v8  : t0 ) : (q0b ? v24 : v16);
        float go = q1b ? (q0b ? t0  : v8 ) : (q0b ? v16 : v24);
        c0 = __builtin_fmaf(gf, c0, gi * gg);
        h0p = go * tanhc(c0);

        // layer1(u-1): inputs h0(u-1)=hk, h1(u-2)=hj
        float a1 = b1s;
        #pragma unroll
        for (int k = 0; k < 8; ++k) a1 = __builtin_fmaf(wi1[k], hk[k], a1);
        #pragma unroll
        for (int k = 0; k < 8; ++k) a1 = __builtin_fmaf(wh1[k], hj[k], a1);
        float t1 = actv(a1);
        float u8  = swz<0x201F>(t1);
        float u16 = swz<0x401F>(t1);
        float u24 = swz<0x601F>(t1);
        float fi = q1b ? (q0b ? u24 : u16) : (q0b ? u8  : t1 );
        float ff = q1b ? (q0b ? u16 : u24) : (q0b ? t1  : u8 );
        float fg = q1b ? (q0b ? u8  : t1 ) : (q0b ? u24 : u16);
        float fo = q1b ? (q0b ? t1  : u8 ) : (q0b ? u16 : u24);
        if (l1on) {
            c1 = __builtin_fmaf(ff, c1, fi * fg);
            h1p = fo * tanhc(c1);
        }
        // projection for step u-2 from hj (no reduce needed: hj is full h1 row)
        if (doproj) {
            float p = br;
            #pragma unroll
            for (int k = 0; k < 8; ++k) p = __builtin_fmaf(wrq[k], hj[k], p);
            if (isl) *op = p;
            op += B_ * 2;
        }
    };

    // prologue: u = 0..7 (compile-time guards)
    #pragma unroll
    for (int k = 0; k < 8; ++k) STEP(xq[k], k > 0, k >= 2, true);
    // main: u = 8..503
    for (int tb = 8; tb < 504; tb += 8) {
        #pragma unroll
        for (int k = 0; k < 8; ++k) STEP(xq[k], true, true, true);
    }
    // epilogue: u = 504..511, no prefetch
    #pragma unroll
    for (int k = 0; k < 8; ++k) STEP(xq[k], true, true, false);

    // tail: layer1(511), proj(510), proj(511)
    {
        float hk[8], hj[8];
        BCAST8(h0p, hk);   // h0(511)
        BCAST8(h1p, hj);   // h1(510)
        float a1 = b1s;
        #pragma unroll
        for (int k = 0; k < 8; ++k) a1 = __builtin_fmaf(wi1[k], hk[k], a1);
        #pragma unroll
        for (int k = 0; k < 8; ++k) a1 = __builtin_fmaf(wh1[k], hj[k], a1);
        float t1 = actv(a1);
        float u8  = swz<0x201F>(t1);
        float u16 = swz<0x401F>(t1);
        float u24 = swz<0x601F>(t1);
        float fi = q1b ? (q0b ? u24 : u16) : (q0b ? u8  : t1 );
        float ff = q1b ? (q0b ? u16 : u24) : (q0b ? t1  : u8 );
        float fg = q1b ? (q0b ? u8  : t1 ) : (q0b ? u24 : u16);
        float fo = q1b ? (q0b ? t1  : u8 ) : (q0b ? u16 : u24);
        c1 = __builtin_fmaf(ff, c1, fi * fg);
        h1p = fo * tanhc(c1);   // h1(511)

        float p = br;
        #pragma unroll
        for (int k = 0; k < 8; ++k) p = __builtin_fmaf(wrq[k], hj[k], p);
        if (isl) *op = p;       // row 510
        op += B_ * 2;

        float hz[8];
        BCAST8(h1p, hz);        // h1(511)
        float p2 = br;
        #pragma unroll
        for (int k = 0; k < 8; ++k) p2 = __builtin_fmaf(wrq[k], hz[k], p2);
        if (isl) *op = p2;      // row 511
    }
}

extern "C" void kernel_launch(void* const* d_in, const int* in_sizes, int n_in,
                              void* d_out, int out_size, void* d_ws, size_t ws_size,
                              hipStream_t stream) {
    (void)in_sizes; (void)n_in; (void)out_size; (void)ws_size;
    const float* x     = (const float*)d_in[0];
    const float* w_ih0 = (const float*)d_in[1];
    const float* w_hh0 = (const float*)d_in[2];
    const float* b_ih0 = (const float*)d_in[3];
    const float* b_hh0 = (const float*)d_in[4];
    const float* w_ih1 = (const float*)d_in[5];
    const float* w_hh1 = (const float*)d_in[6];
    const float* b_ih1 = (const float*)d_in[7];
    const float* b_hh1 = (const float*)d_in[8];
    const float* w_reg = (const float*)d_in[9];
    const float* b_reg = (const float*)d_in[10];
    float* out = (float*)d_out;
    float* xg  = (float*)d_ws;   // 512*256*32*4 = 16 MB scratch

    xg_gemm<<<2048, 256, 0, stream>>>(x, w_ih0, b_ih0, b_hh0, xg);
    lstm_scan<<<128, 64, 0, stream>>>(xg, w_hh0, w_ih1, w_hh1, b_ih1, b_hh1,
                                      w_reg, b_reg, out);
}

// Round 5
// 161.656 us; speedup vs baseline: 2.6859x; 1.1388x over previous
//
#include <hip/hip_runtime.h>

#define S_  512
#define B_  256
#define NIN 180

// ---- DPP ctrl encodings ----
#define QP_X1 0xB1   // quad_perm [1,0,3,2]  -> lane i reads i^1
#define QP_X2 0x4E   // quad_perm [2,3,0,1]  -> i^2
#define QP_X3 0x1B   // quad_perm [3,2,1,0]  -> i^3
#define ROR4  0x124  // row rotate 4 (== xor4 on 8-periodic data, either direction)
#define ROR8  0x128  // row rotate 8 (== xor8 exactly, either direction)

template<int CTRL>
__device__ __forceinline__ float dppf(float x) {
    return __uint_as_float((unsigned)__builtin_amdgcn_update_dpp(
        0, (int)__float_as_uint(x), CTRL, 0xF, 0xF, true));
}

// ======================= Kernel A: input GEMM =======================
// xg_scan[(s*128 + b/2)*64 + lane(g,b)] = sA(g) * (x[s,b,:]·w_ih0[g,:] + b_ih0[g]+b_hh0[g])
// lane(g,b) = (g>>4)*32 + (b&1)*16 + ((g>>3)&1)*8 + (g&7)
__global__ __launch_bounds__(256) void xg_gemm(
    const float* __restrict__ x, const float* __restrict__ w,
    const float* __restrict__ bi, const float* __restrict__ bh,
    float* __restrict__ xg)
{
    __shared__ float wt[NIN][32];   // transposed + pre-scaled by sA(g)
    __shared__ float bias[32];
    const int tid = threadIdx.x;
    for (int idx = tid; idx < NIN * 32; idx += 256) {
        int g = idx / NIN, i = idx - g * NIN;
        float s = ((g >> 3) == 2) ? -2.8853900817779268f : -1.4426950408889634f;
        wt[i][g] = s * w[idx];
    }
    if (tid < 32) {
        float s = ((tid >> 3) == 2) ? -2.8853900817779268f : -1.4426950408889634f;
        bias[tid] = s * (bi[tid] + bh[tid]);
    }
    __syncthreads();

    const int rg = tid >> 3;          // row group: 8 rows
    const int gq = tid & 7;           // gate quad: gates 4*gq..4*gq+3
    const int s  = blockIdx.x;        // grid 512 = S
    const int b0 = rg * 8;
    const float* xr = x + ((size_t)s * B_ + b0) * NIN;

    float4 acc[8];
    #pragma unroll
    for (int rr = 0; rr < 8; ++rr) acc[rr] = float4{0.f, 0.f, 0.f, 0.f};

    #pragma unroll 3
    for (int ii = 0; ii < 45; ++ii) {
        float4 xv[8];
        #pragma unroll
        for (int rr = 0; rr < 8; ++rr)
            xv[rr] = *(const float4*)(xr + (size_t)rr * NIN + 4 * ii);
        #pragma unroll
        for (int e = 0; e < 4; ++e) {
            float4 wv = *(const float4*)&wt[4 * ii + e][gq * 4];
            #pragma unroll
            for (int rr = 0; rr < 8; ++rr) {
                float xe = (e == 0) ? xv[rr].x : (e == 1) ? xv[rr].y
                         : (e == 2) ? xv[rr].z : xv[rr].w;
                acc[rr].x = __builtin_fmaf(xe, wv.x, acc[rr].x);
                acc[rr].y = __builtin_fmaf(xe, wv.y, acc[rr].y);
                acc[rr].z = __builtin_fmaf(xe, wv.z, acc[rr].z);
                acc[rr].w = __builtin_fmaf(xe, wv.w, acc[rr].w);
            }
        }
    }

    float4 bv = *(const float4*)&bias[gq * 4];
    const int b5s = gq >> 2, b3s = (gq >> 1) & 1, j0 = (gq & 1) * 4;
    #pragma unroll
    for (int rr = 0; rr < 8; ++rr) {
        int b = b0 + rr;
        float4 o = {acc[rr].x + bv.x, acc[rr].y + bv.y,
                    acc[rr].z + bv.z, acc[rr].w + bv.w};
        size_t addr = ((size_t)s * 128 + (b >> 1)) * 64
                    + b5s * 32 + (b & 1) * 16 + b3s * 8 + j0;
        *(float4*)(xg + addr) = o;
    }
}

// ======================= Kernel B: fused scan =======================
// 32 lanes/chain, 2 chains/wave. lane = b5*32 + b4*16 + b3*8 + j;
// gate class q = 2*b5+b3 (0=i,1=f,2=g,3=o), gate row g = q*8+j, chain = 2*bid+b4.
// Cross-lane: DPP within 16-rows, __shfl_xor(32) for the cross-half move.
// Pipeline: layer0(u) || layer1(u-1) || proj(u-2).
__global__ __launch_bounds__(64) void lstm_scan(
    const float* __restrict__ xg,
    const float* __restrict__ w_hh0,
    const float* __restrict__ w_ih1, const float* __restrict__ w_hh1,
    const float* __restrict__ b_ih1, const float* __restrict__ b_hh1,
    const float* __restrict__ w_reg, const float* __restrict__ b_reg,
    float* __restrict__ out)
{
    const int lt = threadIdx.x;
    const int j  = lt & 7;
    const int b3 = (lt >> 3) & 1;
    const int b4 = (lt >> 4) & 1;
    const int b5 = (lt >> 5) & 1;
    const int q  = b5 * 2 + b3;
    const int g  = q * 8 + j;
    const bool b3z = (b3 == 0);
    const bool b5z = (b5 == 0);
    const bool isl = (b5 == 0) && (j == 0);
    const int  bid = blockIdx.x;           // 0..127
    const int  chain = bid * 2 + b4;

    const float sA = (q == 2) ? -2.8853900817779268f : -1.4426950408889634f;
    const float aA = (q == 2) ? 2.0f : 1.0f;
    const float bA = (q == 2) ? -1.0f : 0.0f;

    float w0l[8], wi1l[8], wh1l[8], wrl[8];
    #pragma unroll
    for (int m = 0; m < 8; ++m) {
        int k = j ^ m;
        w0l[m]  = sA * w_hh0[g * 8 + k];
        wi1l[m] = sA * w_ih1[g * 8 + k];
        wh1l[m] = sA * w_hh1[g * 8 + k];
        wrl[m]  = w_reg[b3 * 8 + k];       // projection col = b3
    }
    const float b1s = sA * (b_ih1[g] + b_hh1[g]);
    const float br  = b_reg[b3];

    auto actv = [&](float a) {   // input pre-scaled by sA
        return __builtin_fmaf(aA, __builtin_amdgcn_rcpf(1.0f + __builtin_amdgcn_exp2f(a)), bA);
    };
    auto tanhc = [](float c) {
        return __builtin_fmaf(2.0f, __builtin_amdgcn_rcpf(
            1.0f + __builtin_amdgcn_exp2f(-2.8853900817779268f * c)), -1.0f);
    };
    // r[m] = h[j^m] for all lanes (h must be 8-periodic in lanes)
    auto ROTS = [&](float h, float* r) {
        r[0] = h;
        r[1] = dppf<QP_X1>(h);
        r[2] = dppf<QP_X2>(h);
        r[3] = dppf<QP_X3>(h);
        r[4] = dppf<ROR4>(h);
        r[5] = dppf<QP_X1>(r[4]);
        r[6] = dppf<QP_X2>(r[4]);
        r[7] = dppf<QP_X3>(r[4]);
    };
    // t = activated gate value (class q of this lane); update c,h for unit j on every lane
    auto COMBINE = [&](float t, float& cC, float& hO) {
        float tx8  = dppf<ROR8>(t);            // class (b5, !b3)
        float tx32 = __shfl_xor(t, 32, 64);    // class (!b5, b3) -- ds_bpermute, defined semantics
        float tx40 = dppf<ROR8>(tx32);         // class (!b5, !b3)
        float m    = t * tx32;                 // i*g on b3=0 lanes
        float mr   = dppf<ROR8>(m);
        float ig   = b3z ? m : mr;
        float u    = b3z ? tx8 : t;
        float v    = b3z ? tx40 : tx32;
        float f    = b5z ? u : v;
        float o    = b5z ? v : u;
        cC = __builtin_fmaf(f, cC, ig);
        hO = o * tanhc(cC);
    };

    float h0p = 0.f, h1p = 0.f, c0 = 0.f, c1 = 0.f;

    const float* xbase = xg + (size_t)bid * 64 + lt;
    float xq[8];
    #pragma unroll
    for (int k = 0; k < 8; ++k) xq[k] = xbase[(size_t)k * 8192];
    const float* xp = xbase + (size_t)8 * 8192;
    float* op = out + (size_t)chain * 2 + b3;

    auto STEP = [&](float& xr, bool l1on, bool doproj, bool pref) {
        float r0[8], r1[8];
        ROTS(h0p, r0);      // h0(u-1)
        ROTS(h1p, r1);      // h1(u-2)
        float a0 = xr;
        if (pref) { xr = *xp; xp += 8192; }
        #pragma unroll
        for (int m = 0; m < 8; ++m) a0 = __builtin_fmaf(w0l[m], r0[m], a0);
        float t0 = actv(a0);

        float a1 = b1s;
        #pragma unroll
        for (int m = 0; m < 8; ++m) a1 = __builtin_fmaf(wi1l[m], r0[m], a1);
        #pragma unroll
        for (int m = 0; m < 8; ++m) a1 = __builtin_fmaf(wh1l[m], r1[m], a1);
        float t1 = actv(a1);

        if (doproj) {
            float p = br;
            #pragma unroll
            for (int m = 0; m < 8; ++m) p = __builtin_fmaf(wrl[m], r1[m], p);
            if (isl) *op = p;
            op += B_ * 2;
        }
        COMBINE(t0, c0, h0p);              // -> h0(u)
        if (l1on) COMBINE(t1, c1, h1p);    // -> h1(u-1)
    };

    // prologue u=0..7
    #pragma unroll
    for (int k = 0; k < 8; ++k) STEP(xq[k], k > 0, k >= 2, true);
    // main u=8..503
    for (int tb = 8; tb < 504; tb += 8) {
        #pragma unroll
        for (int k = 0; k < 8; ++k) STEP(xq[k], true, true, true);
    }
    // epilogue u=504..511 (no prefetch)
    #pragma unroll
    for (int k = 0; k < 8; ++k) STEP(xq[k], true, true, false);

    // tail: layer1(511) + proj(510), then proj(511)
    {
        float r0[8], r1[8];
        ROTS(h0p, r0);      // h0(511)
        ROTS(h1p, r1);      // h1(510)
        float a1 = b1s;
        #pragma unroll
        for (int m = 0; m < 8; ++m) a1 = __builtin_fmaf(wi1l[m], r0[m], a1);
        #pragma unroll
        for (int m = 0; m < 8; ++m) a1 = __builtin_fmaf(wh1l[m], r1[m], a1);
        float t1 = actv(a1);

        float p = br;
        #pragma unroll
        for (int m = 0; m < 8; ++m) p = __builtin_fmaf(wrl[m], r1[m], p);
        if (isl) *op = p;           // row 510
        op += B_ * 2;

        COMBINE(t1, c1, h1p);       // h1(511)
        float r2[8];
        ROTS(h1p, r2);
        float p2 = br;
        #pragma unroll
        for (int m = 0; m < 8; ++m) p2 = __builtin_fmaf(wrl[m], r2[m], p2);
        if (isl) *op = p2;          // row 511
    }
}

extern "C" void kernel_launch(void* const* d_in, const int* in_sizes, int n_in,
                              void* d_out, int out_size, void* d_ws, size_t ws_size,
                              hipStream_t stream) {
    (void)in_sizes; (void)n_in; (void)out_size; (void)ws_size;
    const float* x     = (const float*)d_in[0];
    const float* w_ih0 = (const float*)d_in[1];
    const float* w_hh0 = (const float*)d_in[2];
    const float* b_ih0 = (const float*)d_in[3];
    const float* b_hh0 = (const float*)d_in[4];
    const float* w_ih1 = (const float*)d_in[5];
    const float* w_hh1 = (const float*)d_in[6];
    const float* b_ih1 = (const float*)d_in[7];
    const float* b_hh1 = (const float*)d_in[8];
    const float* w_reg = (const float*)d_in[9];
    const float* b_reg = (const float*)d_in[10];
    float* out = (float*)d_out;
    float* xg  = (float*)d_ws;   // 512*128*64*4 = 16 MB scratch

    xg_gemm<<<512, 256, 0, stream>>>(x, w_ih0, b_ih0, b_hh0, xg);
    lstm_scan<<<128, 64, 0, stream>>>(xg, w_hh0, w_ih1, w_hh1, b_ih1, b_hh1,
                                      w_reg, b_reg, out);
}